// Round 1
// baseline (669.484 us; speedup 1.0000x reference)
//
#include <hip/hip_runtime.h>
#include <stdint.h>

#define D_MODEL 1024
#define NUM_HEADS 16
#define HEAD_DIM 64
#define BATCH 4
#define SEQ 2048
#define BS (BATCH*SEQ)                    // 8192 rows
#define NX ((size_t)BS*D_MODEL)           // 8388608 elements
#define WELEMS ((size_t)D_MODEL*D_MODEL)  // 1048576 elements

typedef short bf16x8 __attribute__((ext_vector_type(8)));
typedef short bf16x4 __attribute__((ext_vector_type(4)));
typedef float f32x4  __attribute__((ext_vector_type(4)));

__device__ inline float b2f(short u) {
  unsigned x = ((unsigned)(unsigned short)u) << 16;
  union { unsigned u; float f; } c; c.u = x; return c.f;
}
__device__ inline short f2b(float f) {
  union { float f; unsigned u; } c; c.f = f;
  unsigned r = (c.u + 0x7FFFu + ((c.u >> 16) & 1u)) >> 16;
  return (short)r;
}

typedef const __attribute__((address_space(1))) void* gas_t;
typedef __attribute__((address_space(3))) void*       las_t;
__device__ inline void gload16(const void* g, void* l) {
  __builtin_amdgcn_global_load_lds((gas_t)(uintptr_t)g,
                                   (las_t)(uint32_t)(uintptr_t)l, 16, 0, 0);
}

// ---------------------------------------------------------------- prep
// Convert X (fp32, NX) and 4 weight matrices (fp32, WELEMS each) to bf16.
__global__ __launch_bounds__(256) void prep_convert(
    const float* __restrict__ X,
    const float* __restrict__ Wq, const float* __restrict__ Wk,
    const float* __restrict__ Wv, const float* __restrict__ Wo,
    short* __restrict__ Xb, short* __restrict__ Wb)
{
  size_t i = ((size_t)blockIdx.x * 256 + threadIdx.x) * 4;
  const float* src; short* dst; size_t off;
  if (i < NX) { src = X; dst = Xb; off = i; }
  else {
    size_t wi = i - NX;
    int w = (int)(wi >> 20);
    off = wi & (WELEMS - 1);
    src = (w == 0) ? Wq : (w == 1) ? Wk : (w == 2) ? Wv : Wo;
    dst = Wb + (size_t)w * WELEMS;
  }
  float4 v = *(const float4*)(src + off);
  bf16x4 o;
  o[0] = f2b(v.x); o[1] = f2b(v.y); o[2] = f2b(v.z); o[3] = f2b(v.w);
  *(bf16x4*)(dst + off) = o;
}

// Build cos/sin table: tab[s*32+i] = (cos(p*inv_freq[i]), sin(...)).
__global__ __launch_bounds__(256) void rope_table(
    const int* __restrict__ pos, float2* __restrict__ tab)
{
  int idx = blockIdx.x * 256 + threadIdx.x;   // 65536 total
  int s = idx >> 5, i = idx & 31;
  float p = (float)pos[s];
  // theta^(-i/32) = exp2(-i * log2(10000)/32)
  float inv = exp2f(-0.41524101186098287f * (float)i);
  float a = p * inv;
  tab[idx] = make_float2(cosf(a), sinf(a));
}

// ---------------------------------------------------------------- GEMM
// Y[m][n] = sum_k A[m][k] * B[n][k]   (B row-major N x K, i.e. B^T input)
// m97 structure: 128x128 tile, BK=32, 4 waves each 64x64, global_load_lds.
template<bool BF16OUT>
__global__ __launch_bounds__(256) void gemm_bt(
    const short* __restrict__ A, const short* __restrict__ Bw,
    void* __restrict__ outv, const int M, const int N, const int K,
    const size_t strideB, const size_t strideOut)
{
  __shared__ short Ash[128 * 32];
  __shared__ short Bsh[128 * 32];
  const int tid = threadIdx.x;
  const int wid = tid >> 6, lane = tid & 63;
  const int g = lane >> 4, li = lane & 15;
  const int row0 = blockIdx.y * 128, col0 = blockIdx.x * 128;
  const int wr = wid >> 1, wc = wid & 1;
  const short* Bz = Bw + (size_t)blockIdx.z * strideB;

  const short* Ag = A  + (size_t)(row0 + wid * 32 + (lane >> 2)) * K + (lane & 3) * 8;
  const short* Bg = Bz + (size_t)(col0 + wid * 32 + (lane >> 2)) * K + (lane & 3) * 8;
  short* lA = &Ash[wid * 1024];
  short* lB = &Bsh[wid * 1024];

  f32x4 acc[4][4];
#pragma unroll
  for (int i = 0; i < 4; ++i)
#pragma unroll
    for (int j = 0; j < 4; ++j) acc[i][j] = (f32x4){0.f, 0.f, 0.f, 0.f};

  for (int kt = 0; kt < K; kt += 32) {
    gload16(Ag + kt,                 lA);
    gload16(Ag + kt + (size_t)16*K,  lA + 512);
    gload16(Bg + kt,                 lB);
    gload16(Bg + kt + (size_t)16*K,  lB + 512);
    __syncthreads();   // drains vmcnt (global_load_lds) before LDS reads
    bf16x8 af[4], bfv[4];
#pragma unroll
    for (int mm = 0; mm < 4; ++mm)
      af[mm] = *(const bf16x8*)&Ash[(wr * 64 + mm * 16 + li) * 32 + g * 8];
#pragma unroll
    for (int nn = 0; nn < 4; ++nn)
      bfv[nn] = *(const bf16x8*)&Bsh[(wc * 64 + nn * 16 + li) * 32 + g * 8];
#pragma unroll
    for (int mm = 0; mm < 4; ++mm)
#pragma unroll
      for (int nn = 0; nn < 4; ++nn)
        acc[mm][nn] = __builtin_amdgcn_mfma_f32_16x16x32_bf16(
            af[mm], bfv[nn], acc[mm][nn], 0, 0, 0);
    __syncthreads();   // protect LDS from next-iter staging
  }

  if (BF16OUT) {
    short* out = (short*)outv + (size_t)blockIdx.z * strideOut;
#pragma unroll
    for (int mm = 0; mm < 4; ++mm)
#pragma unroll
      for (int nn = 0; nn < 4; ++nn)
#pragma unroll
        for (int j = 0; j < 4; ++j) {
          int r = row0 + wr * 64 + mm * 16 + g * 4 + j;
          int c = col0 + wc * 64 + nn * 16 + li;
          out[(size_t)r * N + c] = f2b(acc[mm][nn][j]);
        }
  } else {
    float* out = (float*)outv;
#pragma unroll
    for (int mm = 0; mm < 4; ++mm)
#pragma unroll
      for (int nn = 0; nn < 4; ++nn)
#pragma unroll
        for (int j = 0; j < 4; ++j) {
          int r = row0 + wr * 64 + mm * 16 + g * 4 + j;
          int c = col0 + wc * 64 + nn * 16 + li;
          out[(size_t)r * N + c] = acc[mm][nn][j];
        }
  }
}

// ---------------------------------------------------------------- RoPE
// In-place on Q (blockIdx.y=0) / K (blockIdx.y=1), bf16x8 per thread.
__global__ __launch_bounds__(256) void rope_apply(
    short* __restrict__ QK, const float2* __restrict__ tab)
{
  size_t idx = (size_t)blockIdx.x * 256 + threadIdx.x;   // NX/8 per tensor
  short* base = QK + (size_t)blockIdx.y * NX + idx * 8;
  size_t e = idx * 8;
  int s  = (int)((e >> 10) & (SEQ - 1));
  int dd = (int)(e & (D_MODEL - 1));
  int i0 = (dd & 63) >> 1;
  const float2* tp = tab + s * 32 + i0;
  bf16x8 v = *(bf16x8*)base;
#pragma unroll
  for (int k = 0; k < 4; ++k) {
    float2 cs = tp[k];
    float ev = b2f(v[2 * k]), ov = b2f(v[2 * k + 1]);
    v[2 * k]     = f2b(ev * cs.x - ov * cs.y);
    v[2 * k + 1] = f2b(ev * cs.y + ov * cs.x);
  }
  *(bf16x8*)base = v;
}

// ---------------------------------------------------------------- V^T
// V (b,s,d) -> Vt (b,h,hd,S) so PV B-fragments are contiguous in global.
__global__ __launch_bounds__(256) void transpose_v(
    const short* __restrict__ V, short* __restrict__ Vt)
{
  __shared__ short tile[64][72];
  const int s0 = blockIdx.x * 64, h = blockIdx.y, b = blockIdx.z;
  const int t = threadIdx.x;
  const short* src = V + ((size_t)(b * SEQ + s0)) * D_MODEL + h * 64;
#pragma unroll
  for (int it = 0; it < 2; ++it) {
    int r = it * 32 + (t >> 3), c0 = (t & 7) * 8;
    *(bf16x8*)&tile[r][c0] = *(const bf16x8*)(src + (size_t)r * D_MODEL + c0);
  }
  __syncthreads();
  short* dst = Vt + ((size_t)(b * NUM_HEADS + h) * 64) * SEQ + s0;
#pragma unroll
  for (int it = 0; it < 2; ++it) {
    int d = it * 32 + (t >> 3), sOff = (t & 7) * 8;
    bf16x8 v;
#pragma unroll
    for (int j = 0; j < 8; ++j) v[j] = tile[sOff + j][d];
    *(bf16x8*)(dst + (size_t)d * SEQ + sOff) = v;
  }
}

// ---------------------------------------------------------------- flash
// Causal flash attention. Block = 4 independent waves; wave owns 16 q rows.
// KV tile = 64. K/Vt fragments straight from global (L1/L2 resident).
__global__ __launch_bounds__(256) void flash_attn(
    const short* __restrict__ Q, const short* __restrict__ K,
    const short* __restrict__ Vt, short* __restrict__ O)
{
  __shared__ short Pl[4][16 * 72];
  const int qt = blockIdx.x, h = blockIdx.y, b = blockIdx.z;
  const int wid = threadIdx.x >> 6, lane = threadIdx.x & 63;
  const int g = lane >> 4, li = lane & 15;
  const int qrow0 = qt * 64 + wid * 16;
  const size_t bS = (size_t)b * SEQ;

  const short* Qp = Q + (bS + qrow0 + li) * D_MODEL + h * 64 + g * 8;
  bf16x8 qa0 = *(const bf16x8*)Qp;
  bf16x8 qa1 = *(const bf16x8*)(Qp + 32);

  f32x4 oacc[4];
#pragma unroll
  for (int n = 0; n < 4; ++n) oacc[n] = (f32x4){0.f, 0.f, 0.f, 0.f};
  float mrow[4] = {-1e30f, -1e30f, -1e30f, -1e30f};
  float lrow[4] = {0.f, 0.f, 0.f, 0.f};

  const short* Kb = K + bS * D_MODEL + h * 64;
  const short* Vb = Vt + ((size_t)(b * NUM_HEADS + h) * 64) * SEQ;
  short* Plw = &Pl[wid][0];

  for (int t = 0; t <= qt; ++t) {
    f32x4 sc[4];
#pragma unroll
    for (int n = 0; n < 4; ++n) sc[n] = (f32x4){0.f, 0.f, 0.f, 0.f};
#pragma unroll
    for (int n = 0; n < 4; ++n) {
      const short* kp = Kb + (size_t)(t * 64 + n * 16 + li) * D_MODEL + g * 8;
      bf16x8 kb0 = *(const bf16x8*)kp;
      bf16x8 kb1 = *(const bf16x8*)(kp + 32);
      sc[n] = __builtin_amdgcn_mfma_f32_16x16x32_bf16(qa0, kb0, sc[n], 0, 0, 0);
      sc[n] = __builtin_amdgcn_mfma_f32_16x16x32_bf16(qa1, kb1, sc[n], 0, 0, 0);
    }
    // scale + causal mask (only diagonal tile needs masking)
    float mxj[4] = {-1e30f, -1e30f, -1e30f, -1e30f};
#pragma unroll
    for (int n = 0; n < 4; ++n)
#pragma unroll
      for (int j = 0; j < 4; ++j) {
        float v = sc[n][j] * 0.125f;
        if (t == qt) {
          int col = t * 64 + n * 16 + li;
          int qr  = qrow0 + g * 4 + j;
          if (col > qr) v = -1e9f;
        }
        sc[n][j] = v;
        mxj[j] = fmaxf(mxj[j], v);
      }
#pragma unroll
    for (int off = 1; off < 16; off <<= 1)
#pragma unroll
      for (int j = 0; j < 4; ++j)
        mxj[j] = fmaxf(mxj[j], __shfl_xor(mxj[j], off, 64));
    float corr[4], rs[4] = {0.f, 0.f, 0.f, 0.f};
#pragma unroll
    for (int j = 0; j < 4; ++j) {
      float mn = fmaxf(mrow[j], mxj[j]);
      corr[j] = __expf(mrow[j] - mn);
      mrow[j] = mn;
    }
#pragma unroll
    for (int n = 0; n < 4; ++n)
#pragma unroll
      for (int j = 0; j < 4; ++j) {
        float p = __expf(sc[n][j] - mrow[j]);
        sc[n][j] = p;
        rs[j] += p;
      }
#pragma unroll
    for (int off = 1; off < 16; off <<= 1)
#pragma unroll
      for (int j = 0; j < 4; ++j) rs[j] += __shfl_xor(rs[j], off, 64);
#pragma unroll
    for (int j = 0; j < 4; ++j) lrow[j] = lrow[j] * corr[j] + rs[j];
#pragma unroll
    for (int n = 0; n < 4; ++n)
#pragma unroll
      for (int j = 0; j < 4; ++j) oacc[n][j] *= corr[j];
    // P -> LDS (row-major [qrow][key]) -> A-fragments
#pragma unroll
    for (int n = 0; n < 4; ++n)
#pragma unroll
      for (int j = 0; j < 4; ++j)
        Plw[(g * 4 + j) * 72 + n * 16 + li] = f2b(sc[n][j]);
    bf16x8 pa0 = *(const bf16x8*)&Plw[li * 72 + g * 8];
    bf16x8 pa1 = *(const bf16x8*)&Plw[li * 72 + 32 + g * 8];
#pragma unroll
    for (int n = 0; n < 4; ++n) {
      const short* vp = Vb + (size_t)(n * 16 + li) * SEQ + t * 64 + g * 8;
      bf16x8 vb0 = *(const bf16x8*)vp;
      bf16x8 vb1 = *(const bf16x8*)(vp + 32);
      oacc[n] = __builtin_amdgcn_mfma_f32_16x16x32_bf16(pa0, vb0, oacc[n], 0, 0, 0);
      oacc[n] = __builtin_amdgcn_mfma_f32_16x16x32_bf16(pa1, vb1, oacc[n], 0, 0, 0);
    }
  }
#pragma unroll
  for (int j = 0; j < 4; ++j) lrow[j] = 1.f / lrow[j];
#pragma unroll
  for (int n = 0; n < 4; ++n)
#pragma unroll
    for (int j = 0; j < 4; ++j)
      O[(bS + qrow0 + g * 4 + j) * D_MODEL + h * 64 + n * 16 + li] =
          f2b(oacc[n][j] * lrow[j]);
}

// ---------------------------------------------------------------- launch
extern "C" void kernel_launch(void* const* d_in, const int* in_sizes, int n_in,
                              void* d_out, int out_size, void* d_ws, size_t ws_size,
                              hipStream_t stream) {
  const float* X  = (const float*)d_in[0];
  const int* pos  = (const int*)d_in[1];
  const float* Wq = (const float*)d_in[2];
  const float* Wk = (const float*)d_in[3];
  const float* Wv = (const float*)d_in[4];
  const float* Wo = (const float*)d_in[5];

  char* ws = (char*)d_ws;
  short*  Xb  = (short*)(ws);                  // NX bf16
  short*  Wb  = (short*)(ws + 16777216);       // 4*WELEMS bf16
  short*  QKV = (short*)(ws + 25165824);       // 3*NX bf16 (Q,K,V)
  short*  Vt  = (short*)(ws + 75497472);       // NX bf16
  short*  Ob  = (short*)(ws + 92274688);       // NX bf16
  float2* tab = (float2*)(ws + 109051904);     // SEQ*32 float2

  prep_convert<<<12288, 256, 0, stream>>>(X, Wq, Wk, Wv, Wo, Xb, Wb);
  rope_table<<<256, 256, 0, stream>>>(pos, tab);
  gemm_bt<true><<<dim3(8, 64, 3), 256, 0, stream>>>(
      Xb, Wb, QKV, BS, D_MODEL, D_MODEL, WELEMS, NX);
  rope_apply<<<dim3(4096, 2, 1), 256, 0, stream>>>(QKV, tab);
  transpose_v<<<dim3(32, 16, 4), 256, 0, stream>>>(QKV + 2 * NX, Vt);
  flash_attn<<<dim3(32, 16, 4), 256, 0, stream>>>(QKV, QKV + NX, Vt, Ob);
  gemm_bt<false><<<dim3(8, 64, 1), 256, 0, stream>>>(
      Ob, Wb + 3 * WELEMS, d_out, BS, D_MODEL, D_MODEL, 0, 0);
}

// Round 2
// 495.841 us; speedup vs baseline: 1.3502x; 1.3502x over previous
//
#include <hip/hip_runtime.h>
#include <stdint.h>

#define D_MODEL 1024
#define NUM_HEADS 16
#define HEAD_DIM 64
#define BATCH 4
#define SEQ 2048
#define BS (BATCH*SEQ)                    // 8192 rows
#define NX ((size_t)BS*D_MODEL)           // 8388608 elements
#define WELEMS ((size_t)D_MODEL*D_MODEL)  // 1048576 elements

typedef short bf16x8 __attribute__((ext_vector_type(8)));
typedef short bf16x4 __attribute__((ext_vector_type(4)));
typedef float f32x4  __attribute__((ext_vector_type(4)));

__device__ inline float b2f(short u) {
  unsigned x = ((unsigned)(unsigned short)u) << 16;
  union { unsigned u; float f; } c; c.u = x; return c.f;
}
__device__ inline short f2b(float f) {
  union { float f; unsigned u; } c; c.f = f;
  unsigned r = (c.u + 0x7FFFu + ((c.u >> 16) & 1u)) >> 16;
  return (short)r;
}
__device__ inline unsigned cvt_pk(float lo, float hi) {
  unsigned r;
  asm("v_cvt_pk_bf16_f32 %0, %1, %2" : "=v"(r) : "v"(lo), "v"(hi));
  return r;
}

typedef const __attribute__((address_space(1))) void* gas_t;
typedef __attribute__((address_space(3))) void*       las_t;
__device__ inline void gload16(const void* g, void* l) {
  __builtin_amdgcn_global_load_lds((gas_t)(uintptr_t)g,
                                   (las_t)(uint32_t)(uintptr_t)l, 16, 0, 0);
}

// ---------------------------------------------------------------- prep
__global__ __launch_bounds__(256) void prep_convert(
    const float* __restrict__ X,
    const float* __restrict__ Wq, const float* __restrict__ Wk,
    const float* __restrict__ Wv, const float* __restrict__ Wo,
    short* __restrict__ Xb, short* __restrict__ Wb)
{
  size_t i = ((size_t)blockIdx.x * 256 + threadIdx.x) * 4;
  const float* src; short* dst; size_t off;
  if (i < NX) { src = X; dst = Xb; off = i; }
  else {
    size_t wi = i - NX;
    int w = (int)(wi >> 20);
    off = wi & (WELEMS - 1);
    src = (w == 0) ? Wq : (w == 1) ? Wk : (w == 2) ? Wv : Wo;
    dst = Wb + (size_t)w * WELEMS;
  }
  float4 v = *(const float4*)(src + off);
  bf16x4 o;
  o[0] = f2b(v.x); o[1] = f2b(v.y); o[2] = f2b(v.z); o[3] = f2b(v.w);
  *(bf16x4*)(dst + off) = o;
}

__global__ __launch_bounds__(256) void rope_table(
    const int* __restrict__ pos, float2* __restrict__ tab)
{
  int idx = blockIdx.x * 256 + threadIdx.x;   // 65536 total
  int s = idx >> 5, i = idx & 31;
  float p = (float)pos[s];
  float inv = exp2f(-0.41524101186098287f * (float)i);
  float a = p * inv;
  tab[idx] = make_float2(cosf(a), sinf(a));
}

// ---------------------------------------------------------------- GEMM
template<bool BF16OUT>
__global__ __launch_bounds__(256) void gemm_bt(
    const short* __restrict__ A, const short* __restrict__ Bw,
    void* __restrict__ outv, const int M, const int N, const int K,
    const size_t strideB, const size_t strideOut)
{
  __shared__ short Ash[128 * 32];
  __shared__ short Bsh[128 * 32];
  const int tid = threadIdx.x;
  const int wid = tid >> 6, lane = tid & 63;
  const int g = lane >> 4, li = lane & 15;
  const int row0 = blockIdx.y * 128, col0 = blockIdx.x * 128;
  const int wr = wid >> 1, wc = wid & 1;
  const short* Bz = Bw + (size_t)blockIdx.z * strideB;

  const short* Ag = A  + (size_t)(row0 + wid * 32 + (lane >> 2)) * K + (lane & 3) * 8;
  const short* Bg = Bz + (size_t)(col0 + wid * 32 + (lane >> 2)) * K + (lane & 3) * 8;
  short* lA = &Ash[wid * 1024];
  short* lB = &Bsh[wid * 1024];

  f32x4 acc[4][4];
#pragma unroll
  for (int i = 0; i < 4; ++i)
#pragma unroll
    for (int j = 0; j < 4; ++j) acc[i][j] = (f32x4){0.f, 0.f, 0.f, 0.f};

  for (int kt = 0; kt < K; kt += 32) {
    gload16(Ag + kt,                 lA);
    gload16(Ag + kt + (size_t)16*K,  lA + 512);
    gload16(Bg + kt,                 lB);
    gload16(Bg + kt + (size_t)16*K,  lB + 512);
    __syncthreads();
    bf16x8 af[4], bfv[4];
#pragma unroll
    for (int mm = 0; mm < 4; ++mm)
      af[mm] = *(const bf16x8*)&Ash[(wr * 64 + mm * 16 + li) * 32 + g * 8];
#pragma unroll
    for (int nn = 0; nn < 4; ++nn)
      bfv[nn] = *(const bf16x8*)&Bsh[(wc * 64 + nn * 16 + li) * 32 + g * 8];
#pragma unroll
    for (int mm = 0; mm < 4; ++mm)
#pragma unroll
      for (int nn = 0; nn < 4; ++nn)
        acc[mm][nn] = __builtin_amdgcn_mfma_f32_16x16x32_bf16(
            af[mm], bfv[nn], acc[mm][nn], 0, 0, 0);
    __syncthreads();
  }

  if (BF16OUT) {
    short* out = (short*)outv + (size_t)blockIdx.z * strideOut;
#pragma unroll
    for (int mm = 0; mm < 4; ++mm)
#pragma unroll
      for (int nn = 0; nn < 4; ++nn)
#pragma unroll
        for (int j = 0; j < 4; ++j) {
          int r = row0 + wr * 64 + mm * 16 + g * 4 + j;
          int c = col0 + wc * 64 + nn * 16 + li;
          out[(size_t)r * N + c] = f2b(acc[mm][nn][j]);
        }
  } else {
    float* out = (float*)outv;
#pragma unroll
    for (int mm = 0; mm < 4; ++mm)
#pragma unroll
      for (int nn = 0; nn < 4; ++nn)
#pragma unroll
        for (int j = 0; j < 4; ++j) {
          int r = row0 + wr * 64 + mm * 16 + g * 4 + j;
          int c = col0 + wc * 64 + nn * 16 + li;
          out[(size_t)r * N + c] = acc[mm][nn][j];
        }
  }
}

// ---------------------------------------------------------------- RoPE
__global__ __launch_bounds__(256) void rope_apply(
    short* __restrict__ QK, const float2* __restrict__ tab)
{
  size_t idx = (size_t)blockIdx.x * 256 + threadIdx.x;
  short* base = QK + (size_t)blockIdx.y * NX + idx * 8;
  size_t e = idx * 8;
  int s  = (int)((e >> 10) & (SEQ - 1));
  int dd = (int)(e & (D_MODEL - 1));
  int i0 = (dd & 63) >> 1;
  const float2* tp = tab + s * 32 + i0;
  bf16x8 v = *(bf16x8*)base;
#pragma unroll
  for (int k = 0; k < 4; ++k) {
    float2 cs = tp[k];
    float ev = b2f(v[2 * k]), ov = b2f(v[2 * k + 1]);
    v[2 * k]     = f2b(ev * cs.x - ov * cs.y);
    v[2 * k + 1] = f2b(ev * cs.y + ov * cs.x);
  }
  *(bf16x8*)base = v;
}

// ---------------------------------------------------------------- V^T
__global__ __launch_bounds__(256) void transpose_v(
    const short* __restrict__ V, short* __restrict__ Vt)
{
  __shared__ short tile[64][72];
  const int s0 = blockIdx.x * 64, h = blockIdx.y, b = blockIdx.z;
  const int t = threadIdx.x;
  const short* src = V + ((size_t)(b * SEQ + s0)) * D_MODEL + h * 64;
#pragma unroll
  for (int it = 0; it < 2; ++it) {
    int r = it * 32 + (t >> 3), c0 = (t & 7) * 8;
    *(bf16x8*)&tile[r][c0] = *(const bf16x8*)(src + (size_t)r * D_MODEL + c0);
  }
  __syncthreads();
  short* dst = Vt + ((size_t)(b * NUM_HEADS + h) * 64) * SEQ + s0;
#pragma unroll
  for (int it = 0; it < 2; ++it) {
    int d = it * 32 + (t >> 3), sOff = (t & 7) * 8;
    bf16x8 v;
#pragma unroll
    for (int j = 0; j < 8; ++j) v[j] = tile[sOff + j][d];
    *(bf16x8*)(dst + (size_t)d * SEQ + sOff) = v;
  }
}

// ---------------------------------------------------------------- flash v2
// Swapped-operand flash: S^T = mfma(K,Q) so each lane owns ONE q-column
// (q = li). Row-reduce = 15 in-reg fmax + 2 shuffles. P write is
// j-contiguous (cvt_pk + ds_write_b64). O^T = mfma(V^T, P^T).
// Wave owns 32 q rows; 4 independent waves/block (no barriers).
#define EXPSCALE 0.18033688011112043f   // log2(e) / sqrt(64)

__global__ __launch_bounds__(256, 2) void flash_attn(
    const short* __restrict__ Q, const short* __restrict__ K,
    const short* __restrict__ Vt, short* __restrict__ O)
{
  __shared__ short Pl[4][32 * 72];
  const int qtb = (int)(gridDim.x - 1 - blockIdx.x);   // long blocks first
  const int h = blockIdx.y, b = blockIdx.z;
  const int wid = threadIdx.x >> 6, lane = threadIdx.x & 63;
  const int g = lane >> 4, li = lane & 15;
  const int qrow0 = qtb * 128 + wid * 32;
  const int tmax = qrow0 >> 6;
  const size_t bS = (size_t)b * SEQ;

  const short* Qb = Q  + (bS + qrow0) * D_MODEL + h * 64;
  const short* Kb = K  + bS * D_MODEL + h * 64;
  const short* Vb = Vt + (size_t)(b * NUM_HEADS + h) * 64 * SEQ;
  short* Pw = &Pl[wid][0];

  // Q B-fragments (held for whole kernel): qb[m][half]
  bf16x8 qb[2][2];
#pragma unroll
  for (int m = 0; m < 2; ++m)
#pragma unroll
    for (int hf = 0; hf < 2; ++hf)
      qb[m][hf] = *(const bf16x8*)(Qb + (size_t)(m * 16 + li) * D_MODEL
                                      + hf * 32 + g * 8);

  f32x4 oacc[2][4];
#pragma unroll
  for (int m = 0; m < 2; ++m)
#pragma unroll
    for (int n = 0; n < 4; ++n) oacc[m][n] = (f32x4){0.f, 0.f, 0.f, 0.f};
  float mrow[2] = {-1e30f, -1e30f};
  float lrow[2] = {0.f, 0.f};

  for (int t = 0; t <= tmax; ++t) {
    // ---- K A-fragments + QK^T (S^T: row k, col q)
    const short* Kt = Kb + (size_t)(t * 64) * D_MODEL;
    bf16x8 kb[4][2];
#pragma unroll
    for (int n = 0; n < 4; ++n)
#pragma unroll
      for (int hf = 0; hf < 2; ++hf)
        kb[n][hf] = *(const bf16x8*)(Kt + (size_t)(n * 16 + li) * D_MODEL
                                        + hf * 32 + g * 8);
    f32x4 sc[2][4];
#pragma unroll
    for (int m = 0; m < 2; ++m)
#pragma unroll
      for (int n = 0; n < 4; ++n) {
        f32x4 a = (f32x4){0.f, 0.f, 0.f, 0.f};
        a = __builtin_amdgcn_mfma_f32_16x16x32_bf16(kb[n][0], qb[m][0], a, 0, 0, 0);
        a = __builtin_amdgcn_mfma_f32_16x16x32_bf16(kb[n][1], qb[m][1], a, 0, 0, 0);
        sc[m][n] = a;
      }
    // ---- prefetch V^T A-fragments (independent of softmax)
    bf16x8 vb[4][2];
#pragma unroll
    for (int n = 0; n < 4; ++n)
#pragma unroll
      for (int hf = 0; hf < 2; ++hf)
        vb[n][hf] = *(const bf16x8*)(Vb + (size_t)(n * 16 + li) * SEQ
                                        + t * 64 + hf * 32 + g * 8);
    // ---- causal mask (raw scores; scale folded into EXPSCALE)
    if (t == tmax) {
#pragma unroll
      for (int m = 0; m < 2; ++m) {
        int qg = qrow0 + m * 16 + li;
#pragma unroll
        for (int n = 0; n < 4; ++n)
#pragma unroll
          for (int j = 0; j < 4; ++j) {
            int kg = t * 64 + n * 16 + g * 4 + j;
            if (kg > qg) sc[m][n][j] = -1e30f;
          }
      }
    }
    // ---- online softmax, lane-local rows
#pragma unroll
    for (int m = 0; m < 2; ++m) {
      float t8[8];
#pragma unroll
      for (int n = 0; n < 4; ++n) {
        t8[n * 2]     = fmaxf(sc[m][n][0], sc[m][n][1]);
        t8[n * 2 + 1] = fmaxf(sc[m][n][2], sc[m][n][3]);
      }
      float t4a = fmaxf(t8[0], t8[1]), t4b = fmaxf(t8[2], t8[3]);
      float t4c = fmaxf(t8[4], t8[5]), t4d = fmaxf(t8[6], t8[7]);
      float pm = fmaxf(fmaxf(t4a, t4b), fmaxf(t4c, t4d));
      pm = fmaxf(pm, __shfl_xor(pm, 16, 64));
      pm = fmaxf(pm, __shfl_xor(pm, 32, 64));
      float mn = fmaxf(mrow[m], pm);
      float corr = exp2f((mrow[m] - mn) * EXPSCALE);
      mrow[m] = mn;
      float s8[8];
#pragma unroll
      for (int n = 0; n < 4; ++n) {
#pragma unroll
        for (int j = 0; j < 4; ++j)
          sc[m][n][j] = exp2f((sc[m][n][j] - mn) * EXPSCALE);
        s8[n * 2]     = sc[m][n][0] + sc[m][n][1];
        s8[n * 2 + 1] = sc[m][n][2] + sc[m][n][3];
      }
      float u4a = s8[0] + s8[1], u4b = s8[2] + s8[3];
      float u4c = s8[4] + s8[5], u4d = s8[6] + s8[7];
      float rs = (u4a + u4b) + (u4c + u4d);
      rs += __shfl_xor(rs, 16, 64);
      rs += __shfl_xor(rs, 32, 64);
      lrow[m] = lrow[m] * corr + rs;
#pragma unroll
      for (int n = 0; n < 4; ++n)
#pragma unroll
        for (int j = 0; j < 4; ++j) oacc[m][n][j] *= corr;
      // P -> LDS row-major [q_local][k], j-contiguous b64 writes
#pragma unroll
      for (int n = 0; n < 4; ++n) {
        uint2 w;
        w.x = cvt_pk(sc[m][n][0], sc[m][n][1]);
        w.y = cvt_pk(sc[m][n][2], sc[m][n][3]);
        *(uint2*)&Pw[(m * 16 + li) * 72 + n * 16 + g * 4] = w;
      }
    }
    // ---- PV: O^T = mfma(V^T, P^T)
    bf16x8 pb[2][2];
#pragma unroll
    for (int m = 0; m < 2; ++m)
#pragma unroll
      for (int hf = 0; hf < 2; ++hf)
        pb[m][hf] = *(const bf16x8*)&Pw[(m * 16 + li) * 72 + hf * 32 + g * 8];
#pragma unroll
    for (int m = 0; m < 2; ++m)
#pragma unroll
      for (int n = 0; n < 4; ++n) {
        oacc[m][n] = __builtin_amdgcn_mfma_f32_16x16x32_bf16(
            vb[n][0], pb[m][0], oacc[m][n], 0, 0, 0);
        oacc[m][n] = __builtin_amdgcn_mfma_f32_16x16x32_bf16(
            vb[n][1], pb[m][1], oacc[m][n], 0, 0, 0);
      }
  }
  // ---- epilogue: O[q][d] = oacc^T / l, packed b64 stores
#pragma unroll
  for (int m = 0; m < 2; ++m) {
    float linv = 1.f / lrow[m];
#pragma unroll
    for (int n = 0; n < 4; ++n) {
      uint2 w;
      w.x = cvt_pk(oacc[m][n][0] * linv, oacc[m][n][1] * linv);
      w.y = cvt_pk(oacc[m][n][2] * linv, oacc[m][n][3] * linv);
      *(uint2*)(O + (bS + qrow0 + m * 16 + li) * D_MODEL
                  + h * 64 + n * 16 + g * 4) = w;
    }
  }
}

// ---------------------------------------------------------------- launch
extern "C" void kernel_launch(void* const* d_in, const int* in_sizes, int n_in,
                              void* d_out, int out_size, void* d_ws, size_t ws_size,
                              hipStream_t stream) {
  const float* X  = (const float*)d_in[0];
  const int* pos  = (const int*)d_in[1];
  const float* Wq = (const float*)d_in[2];
  const float* Wk = (const float*)d_in[3];
  const float* Wv = (const float*)d_in[4];
  const float* Wo = (const float*)d_in[5];

  char* ws = (char*)d_ws;
  short*  Xb  = (short*)(ws);                  // NX bf16
  short*  Wb  = (short*)(ws + 16777216);       // 4*WELEMS bf16
  short*  QKV = (short*)(ws + 25165824);       // 3*NX bf16 (Q,K,V)
  short*  Vt  = (short*)(ws + 75497472);       // NX bf16
  short*  Ob  = (short*)(ws + 92274688);       // NX bf16
  float2* tab = (float2*)(ws + 109051904);     // SEQ*32 float2

  prep_convert<<<12288, 256, 0, stream>>>(X, Wq, Wk, Wv, Wo, Xb, Wb);
  rope_table<<<256, 256, 0, stream>>>(pos, tab);
  gemm_bt<true><<<dim3(8, 64, 3), 256, 0, stream>>>(
      Xb, Wb, QKV, BS, D_MODEL, D_MODEL, WELEMS, NX);
  rope_apply<<<dim3(4096, 2, 1), 256, 0, stream>>>(QKV, tab);
  transpose_v<<<dim3(32, 16, 4), 256, 0, stream>>>(QKV + 2 * NX, Vt);
  flash_attn<<<dim3(16, 16, 4), 256, 0, stream>>>(QKV, QKV + NX, Vt, Ob);
  gemm_bt<false><<<dim3(8, 64, 1), 256, 0, stream>>>(
      Ob, Wb + 3 * WELEMS, d_out, BS, D_MODEL, D_MODEL, 0, 0);
}

// Round 3
// 359.820 us; speedup vs baseline: 1.8606x; 1.3780x over previous
//
#include <hip/hip_runtime.h>
#include <stdint.h>

#define D_MODEL 1024
#define NUM_HEADS 16
#define HEAD_DIM 64
#define BATCH 4
#define SEQ 2048
#define BS (BATCH*SEQ)                    // 8192 rows
#define NX ((size_t)BS*D_MODEL)           // 8388608 elements
#define WELEMS ((size_t)D_MODEL*D_MODEL)  // 1048576 elements

typedef short bf16x8 __attribute__((ext_vector_type(8)));
typedef short bf16x4 __attribute__((ext_vector_type(4)));
typedef float f32x4  __attribute__((ext_vector_type(4)));

__device__ inline float b2f(short u) {
  unsigned x = ((unsigned)(unsigned short)u) << 16;
  union { unsigned u; float f; } c; c.u = x; return c.f;
}
__device__ inline short f2b(float f) {
  union { float f; unsigned u; } c; c.f = f;
  unsigned r = (c.u + 0x7FFFu + ((c.u >> 16) & 1u)) >> 16;
  return (short)r;
}
__device__ inline unsigned cvt_pk(float lo, float hi) {
  unsigned r;
  asm("v_cvt_pk_bf16_f32 %0, %1, %2" : "=v"(r) : "v"(lo), "v"(hi));
  return r;
}

typedef const __attribute__((address_space(1))) void* gas_t;
typedef __attribute__((address_space(3))) void*       las_t;
__device__ inline void gload16(const void* g, void* l) {
  __builtin_amdgcn_global_load_lds((gas_t)(uintptr_t)g,
                                   (las_t)(uint32_t)(uintptr_t)l, 16, 0, 0);
}

// ---------------------------------------------------------------- prep
__global__ __launch_bounds__(256) void prep_convert(
    const float* __restrict__ X,
    const float* __restrict__ Wq, const float* __restrict__ Wk,
    const float* __restrict__ Wv, const float* __restrict__ Wo,
    short* __restrict__ Xb, short* __restrict__ Wb)
{
  size_t i = ((size_t)blockIdx.x * 256 + threadIdx.x) * 4;
  const float* src; short* dst; size_t off;
  if (i < NX) { src = X; dst = Xb; off = i; }
  else {
    size_t wi = i - NX;
    int w = (int)(wi >> 20);
    off = wi & (WELEMS - 1);
    src = (w == 0) ? Wq : (w == 1) ? Wk : (w == 2) ? Wv : Wo;
    dst = Wb + (size_t)w * WELEMS;
  }
  float4 v = *(const float4*)(src + off);
  bf16x4 o;
  o[0] = f2b(v.x); o[1] = f2b(v.y); o[2] = f2b(v.z); o[3] = f2b(v.w);
  *(bf16x4*)(dst + off) = o;
}

__global__ __launch_bounds__(256) void rope_table(
    const int* __restrict__ pos, float2* __restrict__ tab)
{
  int idx = blockIdx.x * 256 + threadIdx.x;   // 65536 total
  int s = idx >> 5, i = idx & 31;
  float p = (float)pos[s];
  float inv = exp2f(-0.41524101186098287f * (float)i);
  float a = p * inv;
  tab[idx] = make_float2(cosf(a), sinf(a));
}

// ---------------------------------------------------------------- GEMM
template<bool BF16OUT>
__global__ __launch_bounds__(256) void gemm_bt(
    const short* __restrict__ A, const short* __restrict__ Bw,
    void* __restrict__ outv, const int M, const int N, const int K,
    const size_t strideB, const size_t strideOut)
{
  __shared__ short Ash[128 * 32];
  __shared__ short Bsh[128 * 32];
  const int tid = threadIdx.x;
  const int wid = tid >> 6, lane = tid & 63;
  const int g = lane >> 4, li = lane & 15;
  const int row0 = blockIdx.y * 128, col0 = blockIdx.x * 128;
  const int wr = wid >> 1, wc = wid & 1;
  const short* Bz = Bw + (size_t)blockIdx.z * strideB;

  const short* Ag = A  + (size_t)(row0 + wid * 32 + (lane >> 2)) * K + (lane & 3) * 8;
  const short* Bg = Bz + (size_t)(col0 + wid * 32 + (lane >> 2)) * K + (lane & 3) * 8;
  short* lA = &Ash[wid * 1024];
  short* lB = &Bsh[wid * 1024];

  f32x4 acc[4][4];
#pragma unroll
  for (int i = 0; i < 4; ++i)
#pragma unroll
    for (int j = 0; j < 4; ++j) acc[i][j] = (f32x4){0.f, 0.f, 0.f, 0.f};

  for (int kt = 0; kt < K; kt += 32) {
    gload16(Ag + kt,                 lA);
    gload16(Ag + kt + (size_t)16*K,  lA + 512);
    gload16(Bg + kt,                 lB);
    gload16(Bg + kt + (size_t)16*K,  lB + 512);
    __syncthreads();
    bf16x8 af[4], bfv[4];
#pragma unroll
    for (int mm = 0; mm < 4; ++mm)
      af[mm] = *(const bf16x8*)&Ash[(wr * 64 + mm * 16 + li) * 32 + g * 8];
#pragma unroll
    for (int nn = 0; nn < 4; ++nn)
      bfv[nn] = *(const bf16x8*)&Bsh[(wc * 64 + nn * 16 + li) * 32 + g * 8];
#pragma unroll
    for (int mm = 0; mm < 4; ++mm)
#pragma unroll
      for (int nn = 0; nn < 4; ++nn)
        acc[mm][nn] = __builtin_amdgcn_mfma_f32_16x16x32_bf16(
            af[mm], bfv[nn], acc[mm][nn], 0, 0, 0);
    __syncthreads();
  }

  if (BF16OUT) {
    short* out = (short*)outv + (size_t)blockIdx.z * strideOut;
#pragma unroll
    for (int mm = 0; mm < 4; ++mm)
#pragma unroll
      for (int nn = 0; nn < 4; ++nn)
#pragma unroll
        for (int j = 0; j < 4; ++j) {
          int r = row0 + wr * 64 + mm * 16 + g * 4 + j;
          int c = col0 + wc * 64 + nn * 16 + li;
          out[(size_t)r * N + c] = f2b(acc[mm][nn][j]);
        }
  } else {
    float* out = (float*)outv;
#pragma unroll
    for (int mm = 0; mm < 4; ++mm)
#pragma unroll
      for (int nn = 0; nn < 4; ++nn)
#pragma unroll
        for (int j = 0; j < 4; ++j) {
          int r = row0 + wr * 64 + mm * 16 + g * 4 + j;
          int c = col0 + wc * 64 + nn * 16 + li;
          out[(size_t)r * N + c] = acc[mm][nn][j];
        }
  }
}

// ---------------------------------------------------------------- RoPE
__global__ __launch_bounds__(256) void rope_apply(
    short* __restrict__ QK, const float2* __restrict__ tab)
{
  size_t idx = (size_t)blockIdx.x * 256 + threadIdx.x;
  short* base = QK + (size_t)blockIdx.y * NX + idx * 8;
  size_t e = idx * 8;
  int s  = (int)((e >> 10) & (SEQ - 1));
  int dd = (int)(e & (D_MODEL - 1));
  int i0 = (dd & 63) >> 1;
  const float2* tp = tab + s * 32 + i0;
  bf16x8 v = *(bf16x8*)base;
#pragma unroll
  for (int k = 0; k < 4; ++k) {
    float2 cs = tp[k];
    float ev = b2f(v[2 * k]), ov = b2f(v[2 * k + 1]);
    v[2 * k]     = f2b(ev * cs.x - ov * cs.y);
    v[2 * k + 1] = f2b(ev * cs.y + ov * cs.x);
  }
  *(bf16x8*)base = v;
}

// ---------------------------------------------------------------- V^T
__global__ __launch_bounds__(256) void transpose_v(
    const short* __restrict__ V, short* __restrict__ Vt)
{
  __shared__ short tile[64][72];
  const int s0 = blockIdx.x * 64, h = blockIdx.y, b = blockIdx.z;
  const int t = threadIdx.x;
  const short* src = V + ((size_t)(b * SEQ + s0)) * D_MODEL + h * 64;
#pragma unroll
  for (int it = 0; it < 2; ++it) {
    int r = it * 32 + (t >> 3), c0 = (t & 7) * 8;
    *(bf16x8*)&tile[r][c0] = *(const bf16x8*)(src + (size_t)r * D_MODEL + c0);
  }
  __syncthreads();
  short* dst = Vt + ((size_t)(b * NUM_HEADS + h) * 64) * SEQ + s0;
#pragma unroll
  for (int it = 0; it < 2; ++it) {
    int d = it * 32 + (t >> 3), sOff = (t & 7) * 8;
    bf16x8 v;
#pragma unroll
    for (int j = 0; j < 8; ++j) v[j] = tile[sOff + j][d];
    *(bf16x8*)(dst + (size_t)d * SEQ + sOff) = v;
  }
}

// ---------------------------------------------------------------- flash v3
// Swapped-operand flash + block-cooperative LDS staging of K/V tiles
// (global_load_lds, double-buffered, pre-swizzled global source so
// ds_read_b128 fragment reads are XOR-despread — rule 21 both-sides).
#define EXPSCALE 0.18033688011112043f   // log2(e) / sqrt(64)
#define MASKV   -30000.0f

__global__ __launch_bounds__(256, 3) void flash_attn(
    const short* __restrict__ Q, const short* __restrict__ K,
    const short* __restrict__ Vt, short* __restrict__ O)
{
  __shared__ short Ksh[2][64 * 64];   // 8KB per buf
  __shared__ short Vsh[2][64 * 64];
  __shared__ short Pl[4][32 * 64];    // per-wave P, XOR-swizzled
  const int qtb = (int)(gridDim.x - 1 - blockIdx.x);   // long blocks first
  const int h = blockIdx.y, b = blockIdx.z;
  const int tid = threadIdx.x;
  const int wid = tid >> 6, lane = tid & 63;
  const int g = lane >> 4, li = lane & 15;
  const int qrow0 = qtb * 128 + wid * 32;
  const int tmaxBlk = 2 * qtb + 1;
  const int wtmax = (qrow0 + 31) >> 6;
  const size_t bS = (size_t)b * SEQ;

  const short* Qb = Q  + (bS + qrow0) * D_MODEL + h * 64;
  const short* Kb = K  + bS * D_MODEL + h * 64;
  const short* Vb = Vt + (size_t)(b * NUM_HEADS + h) * 64 * SEQ;
  short* Pw = &Pl[wid][0];

  // staging geometry: thread -> (row r, dst chunk l&7, src chunk cs)
  const int sl  = lane;
  const int srr = sl >> 3;                 // 0..7 within wave's 8 rows
  const int cs  = (sl & 7) ^ (srr & 7);    // pre-swizzled source chunk
  const int rB  = wid * 8 + srr;           // base row (round 0)

#define STAGE(buf, t) {                                                      \
    const size_t kr0 = (size_t)((t) * 64 + rB) * D_MODEL + cs * 8;           \
    const size_t kr1 = (size_t)((t) * 64 + rB + 32) * D_MODEL + cs * 8;      \
    gload16(Kb + kr0, &Ksh[buf][(wid * 8) * 64]);                            \
    gload16(Kb + kr1, &Ksh[buf][(32 + wid * 8) * 64]);                       \
    const size_t vr0 = (size_t)rB * SEQ + (t) * 64 + cs * 8;                 \
    const size_t vr1 = (size_t)(rB + 32) * SEQ + (t) * 64 + cs * 8;          \
    gload16(Vb + vr0, &Vsh[buf][(wid * 8) * 64]);                            \
    gload16(Vb + vr1, &Vsh[buf][(32 + wid * 8) * 64]);                       \
  }

  // Q B-fragments (held for whole kernel)
  bf16x8 qb[2][2];
#pragma unroll
  for (int m = 0; m < 2; ++m)
#pragma unroll
    for (int hf = 0; hf < 2; ++hf)
      qb[m][hf] = *(const bf16x8*)(Qb + (size_t)(m * 16 + li) * D_MODEL
                                      + hf * 32 + g * 8);

  f32x4 oacc[2][4];
#pragma unroll
  for (int m = 0; m < 2; ++m)
#pragma unroll
    for (int n = 0; n < 4; ++n) oacc[m][n] = (f32x4){0.f, 0.f, 0.f, 0.f};
  float mrow[2] = {MASKV, MASKV};
  float lrow[2] = {0.f, 0.f};

  const int swz = (li & 7) << 3;   // fragment-read XOR (shorts)

  STAGE(0, 0);
  __syncthreads();

  for (int t = 0; t <= tmaxBlk; ++t) {
    const int cur = t & 1;
    if (t < tmaxBlk) STAGE(cur ^ 1, t + 1);

    if (t <= wtmax) {
      const short* Kc = &Ksh[cur][0];
      const short* Vc = &Vsh[cur][0];
      // ---- QK^T (S^T: per-lane q-column = li)
      f32x4 sc[2][4];
      __builtin_amdgcn_s_setprio(1);
#pragma unroll
      for (int n = 0; n < 4; ++n) {
        bf16x8 kb0 = *(const bf16x8*)&Kc[(n * 16 + li) * 64 + (((0 * 4 + g) ^ (li & 7)) << 3)];
        bf16x8 kb1 = *(const bf16x8*)&Kc[(n * 16 + li) * 64 + (((1 * 4 + g) ^ (li & 7)) << 3)];
#pragma unroll
        for (int m = 0; m < 2; ++m) {
          f32x4 a = (f32x4){0.f, 0.f, 0.f, 0.f};
          a = __builtin_amdgcn_mfma_f32_16x16x32_bf16(kb0, qb[m][0], a, 0, 0, 0);
          a = __builtin_amdgcn_mfma_f32_16x16x32_bf16(kb1, qb[m][1], a, 0, 0, 0);
          sc[m][n] = a;
        }
      }
      __builtin_amdgcn_s_setprio(0);
      // ---- causal mask on diagonal tile
      if (t == wtmax) {
#pragma unroll
        for (int m = 0; m < 2; ++m) {
          int qg = qrow0 + m * 16 + li;
#pragma unroll
          for (int n = 0; n < 4; ++n)
#pragma unroll
            for (int j = 0; j < 4; ++j) {
              int kg = t * 64 + n * 16 + g * 4 + j;
              if (kg > qg) sc[m][n][j] = MASKV;
            }
        }
      }
      // ---- online softmax (lane-local row, 2 shuffles), defer-max
#pragma unroll
      for (int m = 0; m < 2; ++m) {
        float a0 = fmaxf(fmaxf(sc[m][0][0], sc[m][0][1]), fmaxf(sc[m][0][2], sc[m][0][3]));
        float a1 = fmaxf(fmaxf(sc[m][1][0], sc[m][1][1]), fmaxf(sc[m][1][2], sc[m][1][3]));
        float a2 = fmaxf(fmaxf(sc[m][2][0], sc[m][2][1]), fmaxf(sc[m][2][2], sc[m][2][3]));
        float a3 = fmaxf(fmaxf(sc[m][3][0], sc[m][3][1]), fmaxf(sc[m][3][2], sc[m][3][3]));
        float pm = fmaxf(fmaxf(a0, a1), fmaxf(a2, a3));
        pm = fmaxf(pm, __shfl_xor(pm, 16, 64));
        pm = fmaxf(pm, __shfl_xor(pm, 32, 64));
        if (!__all(pm <= mrow[m] + 16.6f)) {     // T13 defer-max (P <= 8)
          float mn = fmaxf(mrow[m], pm);
          float corr = exp2f((mrow[m] - mn) * EXPSCALE);
          mrow[m] = mn;
          lrow[m] *= corr;
#pragma unroll
          for (int n = 0; n < 4; ++n)
#pragma unroll
            for (int j = 0; j < 4; ++j) oacc[m][n][j] *= corr;
        }
        float mnS = mrow[m] * EXPSCALE;
        float rs = 0.f;
#pragma unroll
        for (int n = 0; n < 4; ++n) {
#pragma unroll
          for (int j = 0; j < 4; ++j) {
            float p = exp2f(__builtin_fmaf(sc[m][n][j], EXPSCALE, -mnS));
            sc[m][n][j] = p;
            rs += p;
          }
        }
        rs += __shfl_xor(rs, 16, 64);
        rs += __shfl_xor(rs, 32, 64);
        lrow[m] += rs;
        // P -> LDS (XOR-swizzled b64 writes)
#pragma unroll
        for (int n = 0; n < 4; ++n) {
          uint2 w2;
          w2.x = cvt_pk(sc[m][n][0], sc[m][n][1]);
          w2.y = cvt_pk(sc[m][n][2], sc[m][n][3]);
          *(uint2*)&Pw[(m * 16 + li) * 64 + ((n * 16 + g * 4) ^ swz)] = w2;
        }
      }
      // ---- PV: O^T = mfma(V^T, P^T)
      __builtin_amdgcn_s_setprio(1);
#pragma unroll
      for (int n = 0; n < 4; ++n) {
        bf16x8 vb0 = *(const bf16x8*)&Vc[(n * 16 + li) * 64 + (((0 * 4 + g) ^ (li & 7)) << 3)];
        bf16x8 vb1 = *(const bf16x8*)&Vc[(n * 16 + li) * 64 + (((1 * 4 + g) ^ (li & 7)) << 3)];
#pragma unroll
        for (int m = 0; m < 2; ++m) {
          bf16x8 pb0 = *(const bf16x8*)&Pw[(m * 16 + li) * 64 + (((0 * 4 + g) ^ (li & 7)) << 3)];
          bf16x8 pb1 = *(const bf16x8*)&Pw[(m * 16 + li) * 64 + (((1 * 4 + g) ^ (li & 7)) << 3)];
          oacc[m][n] = __builtin_amdgcn_mfma_f32_16x16x32_bf16(vb0, pb0, oacc[m][n], 0, 0, 0);
          oacc[m][n] = __builtin_amdgcn_mfma_f32_16x16x32_bf16(vb1, pb1, oacc[m][n], 0, 0, 0);
        }
      }
      __builtin_amdgcn_s_setprio(0);
    }
    __syncthreads();   // staging of t+1 complete; buf free for t+2
  }

  // ---- epilogue
#pragma unroll
  for (int m = 0; m < 2; ++m) {
    float linv = 1.f / lrow[m];
#pragma unroll
    for (int n = 0; n < 4; ++n) {
      uint2 w2;
      w2.x = cvt_pk(oacc[m][n][0] * linv, oacc[m][n][1] * linv);
      w2.y = cvt_pk(oacc[m][n][2] * linv, oacc[m][n][3] * linv);
      *(uint2*)(O + (bS + qrow0 + m * 16 + li) * D_MODEL
                  + h * 64 + n * 16 + g * 4) = w2;
    }
  }
#undef STAGE
}

// ---------------------------------------------------------------- launch
extern "C" void kernel_launch(void* const* d_in, const int* in_sizes, int n_in,
                              void* d_out, int out_size, void* d_ws, size_t ws_size,
                              hipStream_t stream) {
  const float* X  = (const float*)d_in[0];
  const int* pos  = (const int*)d_in[1];
  const float* Wq = (const float*)d_in[2];
  const float* Wk = (const float*)d_in[3];
  const float* Wv = (const float*)d_in[4];
  const float* Wo = (const float*)d_in[5];

  char* ws = (char*)d_ws;
  short*  Xb  = (short*)(ws);                  // NX bf16
  short*  Wb  = (short*)(ws + 16777216);       // 4*WELEMS bf16
  short*  QKV = (short*)(ws + 25165824);       // 3*NX bf16 (Q,K,V)
  short*  Vt  = (short*)(ws + 75497472);       // NX bf16
  short*  Ob  = (short*)(ws + 92274688);       // NX bf16
  float2* tab = (float2*)(ws + 109051904);     // SEQ*32 float2

  prep_convert<<<12288, 256, 0, stream>>>(X, Wq, Wk, Wv, Wo, Xb, Wb);
  rope_table<<<256, 256, 0, stream>>>(pos, tab);
  gemm_bt<true><<<dim3(8, 64, 3), 256, 0, stream>>>(
      Xb, Wb, QKV, BS, D_MODEL, D_MODEL, WELEMS, NX);
  rope_apply<<<dim3(4096, 2, 1), 256, 0, stream>>>(QKV, tab);
  transpose_v<<<dim3(32, 16, 4), 256, 0, stream>>>(QKV + 2 * NX, Vt);
  flash_attn<<<dim3(16, 16, 4), 256, 0, stream>>>(QKV, QKV + NX, Vt, Ob);
  gemm_bt<false><<<dim3(8, 64, 1), 256, 0, stream>>>(
      Ob, Wb + 3 * WELEMS, d_out, BS, D_MODEL, D_MODEL, 0, 0);
}